// Round 4
// baseline (490.750 us; speedup 1.0000x reference)
//
#include <hip/hip_runtime.h>
#include <stdint.h>

#define D   64
#define D2  128
#define R   196          // nodes per bucket  (512*196 = 100352 >= N)
#define NBK 512          // buckets
#define CAP 4096         // payload slots per bucket (mean 3125, +17 sigma)

// ---------------------------------------------------------------------------
// Embedding-sum table: embsum[code][0:64], code = f0*12 + f1*2 + f2 (60 codes)
// ---------------------------------------------------------------------------
__global__ void k_embsum(
    const float* __restrict__ be0, const float* __restrict__ be1,
    const float* __restrict__ be2, float* __restrict__ embsum)
{
    int c = blockIdx.x;      // 0..59
    int t = threadIdx.x;     // 0..63
    int f0 = c / 12;
    int r  = c % 12;
    int f1 = r / 2;
    int f2 = r % 2;
    embsum[c * D + t] = be0[f0 * D + t] + be1[f1 * D + t] + be2[f2 * D + t];
}

// bcursor[b*16] = b*CAP  (line-padded bump allocators: 1 cursor per 64B line)
__global__ void k_init(int* __restrict__ bcursor)
{
    int i = blockIdx.x * 256 + threadIdx.x;
    if (i < NBK) bcursor[i * 16] = i * CAP;
}

// ---------------------------------------------------------------------------
// Bucket partition: tile of 2048 edges per block, LDS-staged so the global
// payload writes are contiguous runs (avg 4 edges = 16B per bucket per tile).
// payload word: src | (code<<17) | (localdst<<23)   (17+6+8 = 31 bits)
// LDS ~19 KB -> 8 blocks/CU allowed; grid 782 -> ~3/CU resident.
// ---------------------------------------------------------------------------
__global__ __launch_bounds__(256) void k_part(
    const int* __restrict__ ei, const int* __restrict__ ef,
    int* __restrict__ bcursor, int* __restrict__ payload, int E)
{
    __shared__ int scnt[NBK];            // per-tile bucket counts (2 KB)
    __shared__ int sstart[NBK];          // exclusive scan of scnt (2 KB)
    __shared__ int sgbase[NBK];          // reserved global base per bucket (2 KB)
    __shared__ int sdat[2048];           // staged payload words (8 KB)
    __shared__ unsigned short sbkt[2048];// bucket of each staged slot (4 KB)
    __shared__ int sred2[256];           // block-scan partials (1 KB)

    int t = threadIdx.x;
    for (int i = t; i < NBK; i += 256) scnt[i] = 0;
    __syncthreads();

    int base2 = blockIdx.x * 1024;       // pair index base (2 edges/pair)

    int b0[4], p0[4], r0[4];
    int b1[4], p1[4], r1[4];

    #pragma unroll
    for (int k = 0; k < 4; k++) {
        int i2 = base2 + k * 256 + t;
        int e0 = i2 * 2;
        if (e0 < E) {
            int2 d  = ((const int2*)ei)[i2];
            int2 s  = ((const int2*)(ei + E))[i2];
            int2 q0 = ((const int2*)ef)[3 * i2 + 0];
            int2 q1 = ((const int2*)ef)[3 * i2 + 1];
            int2 q2 = ((const int2*)ef)[3 * i2 + 2];
            {
                int bb = d.x / R; if (bb > NBK - 1) bb = NBK - 1;
                int ld = d.x - bb * R;
                int code = q0.x * 12 + q0.y * 2 + q1.x;
                b0[k] = bb;
                p0[k] = s.x | (code << 17) | (ld << 23);
                r0[k] = atomicAdd(&scnt[bb], 1);
            }
            if (e0 + 1 < E) {
                int bb = d.y / R; if (bb > NBK - 1) bb = NBK - 1;
                int ld = d.y - bb * R;
                int code = q1.y * 12 + q2.x * 2 + q2.y;
                b1[k] = bb;
                p1[k] = s.y | (code << 17) | (ld << 23);
                r1[k] = atomicAdd(&scnt[bb], 1);
            }
        }
    }
    __syncthreads();

    // exclusive scan of scnt[0..NBK-1]: thread t owns 2 consecutive buckets
    int c0 = scnt[t * 2], c1 = scnt[t * 2 + 1];
    sred2[t] = c0 + c1;
    __syncthreads();
    int sv = sred2[t];
    for (int off = 1; off < 256; off <<= 1) {
        int x = (t >= off) ? sred2[t - off] : 0;
        __syncthreads();
        sred2[t] += x;
        __syncthreads();
    }
    int excl = sred2[t] - sv;
    sstart[t * 2]     = excl;
    sstart[t * 2 + 1] = excl + c0;
    __syncthreads();

    // reserve global space: one atomic per non-empty bucket (padded cursors)
    for (int i = t; i < NBK; i += 256) {
        int c = scnt[i];
        if (c) sgbase[i] = atomicAdd(&bcursor[i * 16], c);
    }
    __syncthreads();

    // place edges into staged slots (dense: sstart[b] + rank)
    #pragma unroll
    for (int k = 0; k < 4; k++) {
        int i2 = base2 + k * 256 + t;
        int e0 = i2 * 2;
        if (e0 < E) {
            int slot = sstart[b0[k]] + r0[k];
            sdat[slot] = p0[k]; sbkt[slot] = (unsigned short)b0[k];
            if (e0 + 1 < E) {
                slot = sstart[b1[k]] + r1[k];
                sdat[slot] = p1[k]; sbkt[slot] = (unsigned short)b1[k];
            }
        }
    }
    __syncthreads();

    // flush: thread-linear over staged slots -> contiguous runs per bucket
    int tc = E - base2 * 2; if (tc > 2048) tc = 2048;
    #pragma unroll
    for (int k = 0; k < 8; k++) {
        int i = k * 256 + t;
        if (i < tc) {
            int bb = sbkt[i];
            int pos = sgbase[bb] + (i - sstart[bb]);
            if (pos < (bb + 1) * CAP) payload[pos] = sdat[i];
        }
    }
}

// ---------------------------------------------------------------------------
// Per-bucket: counting-sort payload by localdst in LDS (scalar int atomics
// only), then register-accumulate reduce wave-per-node (batch ds_read +
// __shfl distribution + 4-way unrolled gathers). No wave64 LDS f32 atomics.
// LDS: sE 15360 + sp/sq 32768 + scan ~2.6 KB = 50.7 KB -> 3 blocks/CU
// allowed; grid 512 x 512 threads -> 2 blocks/CU = 16 waves/CU (50%).
// ---------------------------------------------------------------------------
__global__ __launch_bounds__(512) void k_sortred(
    const float* __restrict__ nf,
    const int* __restrict__ bcursor,
    const int* __restrict__ payload,
    const float* __restrict__ embsum,
    const float* __restrict__ epsp,
    float* __restrict__ h, int N)
{
    __shared__ float sE[60 * D];     // 15360 B
    __shared__ int   sp[CAP];        // 16384 B  raw bucket payload
    __shared__ int   sq[CAP];        // 16384 B  sorted by localdst
    __shared__ int   scn[R + 1];     // node start offsets
    __shared__ int   scur[R];        // scatter cursors
    __shared__ int   sscan[256];     // scan workspace

    int tid = threadIdx.x;
    int b = blockIdx.x;
    int n0 = b * R;

    for (int i = tid; i < 60 * D; i += 512) sE[i] = embsum[i];
    if (tid <= R) scn[tid] = 0;
    __syncthreads();

    int js = b * CAP;
    int cnt = bcursor[b * 16] - js;
    if (cnt > CAP) cnt = CAP;
    if (cnt < 0) cnt = 0;

    // load + per-node count (scalar int LDS atomics; counts at scn[ld+1])
    for (int i = tid; i < cnt; i += 512) {
        int u = payload[js + i];
        sp[i] = u;
        atomicAdd(&scn[((unsigned)u >> 23) + 1], 1);
    }
    __syncthreads();

    // inclusive scan over 256 entries (R+1=197 live) -> scn[k] = start of node k
    if (tid < 256) sscan[tid] = (tid <= R) ? scn[tid] : 0;
    __syncthreads();
    for (int off = 1; off < 256; off <<= 1) {
        int x = 0;
        if (tid < 256 && tid >= off) x = sscan[tid - off];
        __syncthreads();
        if (tid < 256) sscan[tid] += x;
        __syncthreads();
    }
    if (tid <= R) {
        scn[tid] = sscan[tid];
        if (tid < R) scur[tid] = sscan[tid];
    }
    __syncthreads();

    // scatter into sorted order (scalar int LDS atomics on cursors)
    for (int i = tid; i < cnt; i += 512) {
        int u = sp[i];
        int pos = atomicAdd(&scur[(unsigned)u >> 23], 1);
        sq[pos] = u;
    }
    __syncthreads();

    // wave-per-node register-accumulate reduce
    int w = tid >> 6, l = tid & 63;
    float epsv = 1.0f + epsp[0];
    for (int r = w; r < R; r += 8) {
        int n = n0 + r;
        if (n >= N) break;
        int st = scn[r], en = scn[r + 1];
        float acc = 0.0f;
        for (int jb = st; jb < en; jb += 64) {
            int u = (jb + l < en) ? sq[jb + l] : 0;   // LDS batch, stride-1
            int m = en - jb; if (m > 64) m = 64;
            int t = 0;
            for (; t + 4 <= m; t += 4) {
                int a0 = __shfl(u, t + 0);
                int a1 = __shfl(u, t + 1);
                int a2 = __shfl(u, t + 2);
                int a3 = __shfl(u, t + 3);
                float x0 = nf[(size_t)(a0 & 0x1FFFF) * D + l];
                float x1 = nf[(size_t)(a1 & 0x1FFFF) * D + l];
                float x2 = nf[(size_t)(a2 & 0x1FFFF) * D + l];
                float x3 = nf[(size_t)(a3 & 0x1FFFF) * D + l];
                float e0 = sE[((a0 >> 17) & 63) * D + l];
                float e1 = sE[((a1 >> 17) & 63) * D + l];
                float e2 = sE[((a2 >> 17) & 63) * D + l];
                float e3 = sE[((a3 >> 17) & 63) * D + l];
                acc += fmaxf(x0 + e0, 0.0f) + fmaxf(x1 + e1, 0.0f)
                     + fmaxf(x2 + e2, 0.0f) + fmaxf(x3 + e3, 0.0f);
            }
            for (; t < m; t++) {
                int a = __shfl(u, t);
                acc += fmaxf(nf[(size_t)(a & 0x1FFFF) * D + l]
                             + sE[((a >> 17) & 63) * D + l], 0.0f);
            }
        }
        h[(size_t)n * D + l] = fmaf(epsv, nf[(size_t)n * D + l], acc);
    }
}

// ---------------------------------------------------------------------------
// BN stats, syrk-style: per-block register-accumulated partials of
// M = sum_n h_n h_n^T (64x64, 16x16 threads x 4x4 regs) and s = sum_n h_n.
// ---------------------------------------------------------------------------
__global__ __launch_bounds__(256) void k_stats(
    const float* __restrict__ h,
    float* __restrict__ pM,     // [grid][4160]: M (4096) then s (64)
    int N, int tiles)
{
    __shared__ float sH[64 * 68];   // 17408 B
    __shared__ float sred[4 * 64];
    int tid = threadIdx.x;
    int iB = tid >> 4, jB = tid & 15;
    int rg = tid >> 6, lc = tid & 63;

    float M[4][4];
    #pragma unroll
    for (int a = 0; a < 4; a++)
        #pragma unroll
        for (int b = 0; b < 4; b++) M[a][b] = 0.0f;
    float sp = 0.0f;

    for (int t = blockIdx.x; t < tiles; t += gridDim.x) {
        int row0 = t * 64;
        __syncthreads();
        {
            int r = tid >> 2, c16 = (tid & 3) * 16;
            int gr = row0 + r;
            float* dp = &sH[r * 68 + c16];
            if (gr < N) {
                const float4* hr = (const float4*)(h + (size_t)gr * D + c16);
                #pragma unroll
                for (int m2 = 0; m2 < 4; m2++) ((float4*)dp)[m2] = hr[m2];
            } else {
                #pragma unroll
                for (int m2 = 0; m2 < 16; m2++) dp[m2] = 0.0f;
            }
        }
        __syncthreads();

        #pragma unroll 8
        for (int n2 = 0; n2 < 64; n2++) {
            float4 a = *(const float4*)&sH[n2 * 68 + iB * 4];
            float4 b = *(const float4*)&sH[n2 * 68 + jB * 4];
            M[0][0] = fmaf(a.x, b.x, M[0][0]);
            M[0][1] = fmaf(a.x, b.y, M[0][1]);
            M[0][2] = fmaf(a.x, b.z, M[0][2]);
            M[0][3] = fmaf(a.x, b.w, M[0][3]);
            M[1][0] = fmaf(a.y, b.x, M[1][0]);
            M[1][1] = fmaf(a.y, b.y, M[1][1]);
            M[1][2] = fmaf(a.y, b.z, M[1][2]);
            M[1][3] = fmaf(a.y, b.w, M[1][3]);
            M[2][0] = fmaf(a.z, b.x, M[2][0]);
            M[2][1] = fmaf(a.z, b.y, M[2][1]);
            M[2][2] = fmaf(a.z, b.z, M[2][2]);
            M[2][3] = fmaf(a.z, b.w, M[2][3]);
            M[3][0] = fmaf(a.w, b.x, M[3][0]);
            M[3][1] = fmaf(a.w, b.y, M[3][1]);
            M[3][2] = fmaf(a.w, b.z, M[3][2]);
            M[3][3] = fmaf(a.w, b.w, M[3][3]);
        }
        #pragma unroll
        for (int r2 = 0; r2 < 16; r2++)
            sp += sH[(rg * 16 + r2) * 68 + lc];
    }

    float* P = pM + (size_t)blockIdx.x * 4160;
    #pragma unroll
    for (int a = 0; a < 4; a++)
        #pragma unroll
        for (int b = 0; b < 4; b++)
            P[(iB * 4 + a) * 64 + jB * 4 + b] = M[a][b];
    sred[rg * 64 + lc] = sp;
    __syncthreads();
    if (tid < 64)
        P[4096 + tid] = sred[tid] + sred[64 + tid] + sred[128 + tid] + sred[192 + tid];
}

// Reduce partials over blocks; pre-normalize by 1/N.
__global__ __launch_bounds__(256) void k_redM(
    const float* __restrict__ pM, int nblk,
    float* __restrict__ Mbar, float invN)
{
    int e = blockIdx.x * 256 + threadIdx.x;
    if (e >= 4160) return;
    float s = 0.0f;
    for (int b = 0; b < nblk; b++) s += pM[(size_t)b * 4160 + e];
    Mbar[e] = s * invN;
}

// Per-channel BN scale/shift: var_c = w^T Mbar w - (w.sbar)^2, mean = w.sbar+b1.
__global__ void k_bn(
    const float* __restrict__ Mbar,   // [4160]: M (64x64) then sbar (64)
    const float* __restrict__ W1,     // [128,64]
    const float* __restrict__ b1,
    const float* __restrict__ gamma, const float* __restrict__ beta,
    float* __restrict__ ss)
{
    __shared__ float sMb[4160];
    int tid = threadIdx.x;  // 128 threads
    for (int i = tid; i < 4160; i += 128) sMb[i] = Mbar[i];
    __syncthreads();

    int c = tid;
    float w[64];
    #pragma unroll
    for (int k = 0; k < 64; k++) w[k] = W1[c * D + k];

    float d = 0.0f;
    #pragma unroll
    for (int k = 0; k < 64; k++) d = fmaf(w[k], sMb[4096 + k], d);

    float Q = 0.0f;
    for (int k = 0; k < 64; k++) {
        float tk = 0.0f;
        #pragma unroll
        for (int j = 0; j < 64; j++) tk = fmaf(sMb[k * 64 + j], w[j], tk);
        Q = fmaf(w[k], tk, Q);
    }

    float var  = fmaxf(Q - d * d, 0.0f);
    float mean = d + b1[c];
    float sc   = gamma[c] * rsqrtf(var + 1e-5f);
    ss[c]       = sc;
    ss[128 + c] = beta[c] - mean * sc;
}

// ---------------------------------------------------------------------------
// GEMM2: persistent blocks, 32-row tiles.
// LDS = AB 16K + W1t 32K + W2t 32K = 80 KB -> 2 blocks/CU = 8 waves/CU
// (was 96 KB -> 1 block/CU = 1 wave/SIMD, zero latency hiding).
// ---------------------------------------------------------------------------
__global__ __launch_bounds__(256) void k_gemm2(
    const float* __restrict__ h,
    const float* __restrict__ W1,    // [128,64]
    const float* __restrict__ b1,    // [128]
    const float* __restrict__ ss,    // scale/shift [256]
    const float* __restrict__ W2,    // [64,128]
    const float* __restrict__ b2v,   // [64]
    float* __restrict__ out,         // [N,64]
    int N, int tiles)
{
    __shared__ float AB[32 * 128];
    __shared__ float W1t[64 * 128];
    __shared__ float W2t[128 * 64];

    int tid = threadIdx.x;
    int ty = tid >> 5, tx = tid & 31;

    {   // stage W1^T: W1t[k][c]
        int c  = tid >> 1;
        int k0 = (tid & 1) * 32;
        const float4* wr = (const float4*)(W1 + c * D + k0);
        #pragma unroll
        for (int q = 0; q < 8; q++) {
            float4 u = wr[q];
            int k = k0 + q * 4;
            W1t[(k + 0) * 128 + c] = u.x;
            W1t[(k + 1) * 128 + c] = u.y;
            W1t[(k + 2) * 128 + c] = u.z;
            W1t[(k + 3) * 128 + c] = u.w;
        }
    }
    {   // stage W2^T: W2t[k][j]
        int j  = tid >> 2;
        int k0 = (tid & 3) * 32;
        const float4* wr = (const float4*)(W2 + j * D2 + k0);
        #pragma unroll
        for (int q = 0; q < 8; q++) {
            float4 u = wr[q];
            int k = k0 + q * 4;
            W2t[(k + 0) * 64 + j] = u.x;
            W2t[(k + 1) * 64 + j] = u.y;
            W2t[(k + 2) * 64 + j] = u.z;
            W2t[(k + 3) * 64 + j] = u.w;
        }
    }

    float bb0 = b1[tx * 4 + 0];
    float bb1 = b1[tx * 4 + 1];
    float bb2 = b1[tx * 4 + 2];
    float bb3 = b1[tx * 4 + 3];
    float4 scv = *(const float4*)&ss[tx * 4];
    float4 shv = *(const float4*)&ss[128 + tx * 4];
    float ob0 = b2v[tx * 2 + 0];
    float ob1 = b2v[tx * 2 + 1];

    for (int t = blockIdx.x; t < tiles; t += gridDim.x) {
        int row0 = t * 32;
        __syncthreads();
        {   // phase A: stage h tile, 32 rows x 64 cols (8 floats/thread)
            int r  = tid >> 3;
            int c8 = (tid & 7) * 8;
            int gr = row0 + r;
            float* dstp = &AB[r * 128 + c8];
            if (gr < N) {
                const float4* hrow = (const float4*)(h + (size_t)gr * D + c8);
                ((float4*)dstp)[0] = hrow[0];
                ((float4*)dstp)[1] = hrow[1];
            } else {
                #pragma unroll
                for (int m = 0; m < 8; m++) dstp[m] = 0.0f;
            }
        }
        __syncthreads();

        float acc[4][4];
        #pragma unroll
        for (int i = 0; i < 4; i++)
            #pragma unroll
            for (int j = 0; j < 4; j++) acc[i][j] = 0.0f;

        #pragma unroll 4
        for (int k4 = 0; k4 < 16; k4++) {
            float4 w0 = *(const float4*)&W1t[(k4 * 4 + 0) * 128 + tx * 4];
            float4 w1 = *(const float4*)&W1t[(k4 * 4 + 1) * 128 + tx * 4];
            float4 w2 = *(const float4*)&W1t[(k4 * 4 + 2) * 128 + tx * 4];
            float4 w3 = *(const float4*)&W1t[(k4 * 4 + 3) * 128 + tx * 4];
            #pragma unroll
            for (int i = 0; i < 4; i++) {
                float4 a = *(const float4*)&AB[(ty * 4 + i) * 128 + k4 * 4];
                acc[i][0] = fmaf(a.x, w0.x, acc[i][0]);
                acc[i][1] = fmaf(a.x, w0.y, acc[i][1]);
                acc[i][2] = fmaf(a.x, w0.z, acc[i][2]);
                acc[i][3] = fmaf(a.x, w0.w, acc[i][3]);
                acc[i][0] = fmaf(a.y, w1.x, acc[i][0]);
                acc[i][1] = fmaf(a.y, w1.y, acc[i][1]);
                acc[i][2] = fmaf(a.y, w1.z, acc[i][2]);
                acc[i][3] = fmaf(a.y, w1.w, acc[i][3]);
                acc[i][0] = fmaf(a.z, w2.x, acc[i][0]);
                acc[i][1] = fmaf(a.z, w2.y, acc[i][1]);
                acc[i][2] = fmaf(a.z, w2.z, acc[i][2]);
                acc[i][3] = fmaf(a.z, w2.w, acc[i][3]);
                acc[i][0] = fmaf(a.w, w3.x, acc[i][0]);
                acc[i][1] = fmaf(a.w, w3.y, acc[i][1]);
                acc[i][2] = fmaf(a.w, w3.z, acc[i][2]);
                acc[i][3] = fmaf(a.w, w3.w, acc[i][3]);
            }
        }
        __syncthreads();

        #pragma unroll
        for (int i = 0; i < 4; i++) {
            float g0 = fmaxf(fmaf(acc[i][0] + bb0, scv.x, shv.x), 0.0f);
            float g1 = fmaxf(fmaf(acc[i][1] + bb1, scv.y, shv.y), 0.0f);
            float g2 = fmaxf(fmaf(acc[i][2] + bb2, scv.z, shv.z), 0.0f);
            float g3 = fmaxf(fmaf(acc[i][3] + bb3, scv.w, shv.w), 0.0f);
            *(float4*)&AB[(ty * 4 + i) * 128 + tx * 4] = make_float4(g0, g1, g2, g3);
        }
        __syncthreads();

        float acc2[4][2];
        #pragma unroll
        for (int i = 0; i < 4; i++) { acc2[i][0] = 0.0f; acc2[i][1] = 0.0f; }

        #pragma unroll 4
        for (int k4 = 0; k4 < 32; k4++) {
            float2 u0 = *(const float2*)&W2t[(k4 * 4 + 0) * 64 + tx * 2];
            float2 u1 = *(const float2*)&W2t[(k4 * 4 + 1) * 64 + tx * 2];
            float2 u2 = *(const float2*)&W2t[(k4 * 4 + 2) * 64 + tx * 2];
            float2 u3 = *(const float2*)&W2t[(k4 * 4 + 3) * 64 + tx * 2];
            #pragma unroll
            for (int i = 0; i < 4; i++) {
                float4 b = *(const float4*)&AB[(ty * 4 + i) * 128 + k4 * 4];
                acc2[i][0] = fmaf(b.x, u0.x, acc2[i][0]);
                acc2[i][1] = fmaf(b.x, u0.y, acc2[i][1]);
                acc2[i][0] = fmaf(b.y, u1.x, acc2[i][0]);
                acc2[i][1] = fmaf(b.y, u1.y, acc2[i][1]);
                acc2[i][0] = fmaf(b.z, u2.x, acc2[i][0]);
                acc2[i][1] = fmaf(b.z, u2.y, acc2[i][1]);
                acc2[i][0] = fmaf(b.w, u3.x, acc2[i][0]);
                acc2[i][1] = fmaf(b.w, u3.y, acc2[i][1]);
            }
        }

        #pragma unroll
        for (int i = 0; i < 4; i++) {
            int gr = row0 + ty * 4 + i;
            if (gr < N) {
                float2 pk = make_float2(acc2[i][0] + ob0, acc2[i][1] + ob1);
                ((float2*)out)[(size_t)gr * 32 + tx] = pk;
            }
        }
    }
}

// ---------------------------------------------------------------------------
extern "C" void kernel_launch(void* const* d_in, const int* in_sizes, int n_in,
                              void* d_out, int out_size, void* d_ws, size_t ws_size,
                              hipStream_t stream)
{
    const float* nf    = (const float*)d_in[0];
    const int*   ef    = (const int*)d_in[1];
    const int*   ei    = (const int*)d_in[2];
    const float* epsp  = (const float*)d_in[5];
    const float* be0   = (const float*)d_in[6];
    const float* be1   = (const float*)d_in[7];
    const float* be2   = (const float*)d_in[8];
    const float* W1    = (const float*)d_in[9];
    const float* b1    = (const float*)d_in[10];
    const float* gamma = (const float*)d_in[11];
    const float* beta  = (const float*)d_in[12];
    const float* W2    = (const float*)d_in[13];
    const float* b2v   = (const float*)d_in[14];
    float*       out   = (float*)d_out;

    int N = in_sizes[0] / D;    // 100000
    int E = in_sizes[1] / 3;    // 1600000

    int gS = 512;                         // k_stats blocks (2 blocks/CU)
    int tilesS = (N + 63) / 64;           // 1563
    int tiles2 = (N + 31) / 32;           // 3125 (32-row tiles)
    int g2 = 512;                         // 2 blocks/CU (80 KB LDS)

    // workspace layout (4-byte elements); pM aliases payload (payload is
    // dead after k_sortred, pM written by k_stats afterwards; pM is larger)
    float* h       = (float*)d_ws;                    // N*64
    float* Mbar    = h + (size_t)N * D;               // 4160
    float* ss      = Mbar + 4160;                     // 256
    float* embsum  = ss + 256;                        // 60*64
    int*   bcursor = (int*)(embsum + 60 * D);         // NBK*16 (line-padded)
    int*   payload = bcursor + NBK * 16;              // NBK*CAP = 2,097,152
    float* pM      = (float*)payload;                 // gS*4160 = 2,129,920

    k_init<<<2, 256, 0, stream>>>(bcursor);
    k_embsum<<<60, 64, 0, stream>>>(be0, be1, be2, embsum);

    int E2 = (E + 1) / 2;
    int gP = (E2 + 1023) / 1024;          // 782 tiles of 2048 edges
    k_part<<<gP, 256, 0, stream>>>(ei, ef, bcursor, payload, E);

    k_sortred<<<NBK, 512, 0, stream>>>(nf, bcursor, payload, embsum, epsp, h, N);

    k_stats<<<gS, 256, 0, stream>>>(h, pM, N, tilesS);
    k_redM<<<(4160 + 255) / 256, 256, 0, stream>>>(pM, gS, Mbar, 1.0f / (float)N);
    k_bn<<<1, 128, 0, stream>>>(Mbar, W1, b1, gamma, beta, ss);

    k_gemm2<<<g2, 256, 0, stream>>>(h, W1, b1, ss, W2, b2v, out, N, tiles2);
}

// Round 5
// 377.936 us; speedup vs baseline: 1.2985x; 1.2985x over previous
//
#include <hip/hip_runtime.h>
#include <stdint.h>

#define D   64
#define D2  128
#define R   196          // nodes per bucket  (512*196 = 100352 >= N)
#define NBK 512          // buckets
#define CAP 4096         // payload slots per bucket (mean 3125, +17 sigma)

// ---------------------------------------------------------------------------
// Embedding-sum table: embsum[code][0:64], code = f0*12 + f1*2 + f2 (60 codes)
// ---------------------------------------------------------------------------
__global__ void k_embsum(
    const float* __restrict__ be0, const float* __restrict__ be1,
    const float* __restrict__ be2, float* __restrict__ embsum)
{
    int c = blockIdx.x;      // 0..59
    int t = threadIdx.x;     // 0..63
    int f0 = c / 12;
    int r  = c % 12;
    int f1 = r / 2;
    int f2 = r % 2;
    embsum[c * D + t] = be0[f0 * D + t] + be1[f1 * D + t] + be2[f2 * D + t];
}

// bcursor[b*16] = b*CAP  (line-padded bump allocators: 1 cursor per 64B line)
__global__ void k_init(int* __restrict__ bcursor)
{
    int i = blockIdx.x * 256 + threadIdx.x;
    if (i < NBK) bcursor[i * 16] = i * CAP;
}

// ---------------------------------------------------------------------------
// Bucket partition: tile of 2048 edges per block, LDS-staged so the global
// payload writes are contiguous runs (avg 4 edges = 16B per bucket per tile).
// payload word: src | (code<<17) | (localdst<<23)   (17+6+8 = 31 bits)
// ---------------------------------------------------------------------------
__global__ __launch_bounds__(256) void k_part(
    const int* __restrict__ ei, const int* __restrict__ ef,
    int* __restrict__ bcursor, int* __restrict__ payload, int E)
{
    __shared__ int scnt[NBK];            // per-tile bucket counts (2 KB)
    __shared__ int sstart[NBK];          // exclusive scan of scnt (2 KB)
    __shared__ int sgbase[NBK];          // reserved global base per bucket (2 KB)
    __shared__ int sdat[2048];           // staged payload words (8 KB)
    __shared__ unsigned short sbkt[2048];// bucket of each staged slot (4 KB)
    __shared__ int sred2[256];           // block-scan partials (1 KB)

    int t = threadIdx.x;
    for (int i = t; i < NBK; i += 256) scnt[i] = 0;
    __syncthreads();

    int base2 = blockIdx.x * 1024;       // pair index base (2 edges/pair)

    int b0[4], p0[4], r0[4];
    int b1[4], p1[4], r1[4];

    #pragma unroll
    for (int k = 0; k < 4; k++) {
        int i2 = base2 + k * 256 + t;
        int e0 = i2 * 2;
        if (e0 < E) {
            int2 d  = ((const int2*)ei)[i2];
            int2 s  = ((const int2*)(ei + E))[i2];
            int2 q0 = ((const int2*)ef)[3 * i2 + 0];
            int2 q1 = ((const int2*)ef)[3 * i2 + 1];
            int2 q2 = ((const int2*)ef)[3 * i2 + 2];
            {
                int bb = d.x / R; if (bb > NBK - 1) bb = NBK - 1;
                int ld = d.x - bb * R;
                int code = q0.x * 12 + q0.y * 2 + q1.x;
                b0[k] = bb;
                p0[k] = s.x | (code << 17) | (ld << 23);
                r0[k] = atomicAdd(&scnt[bb], 1);
            }
            if (e0 + 1 < E) {
                int bb = d.y / R; if (bb > NBK - 1) bb = NBK - 1;
                int ld = d.y - bb * R;
                int code = q1.y * 12 + q2.x * 2 + q2.y;
                b1[k] = bb;
                p1[k] = s.y | (code << 17) | (ld << 23);
                r1[k] = atomicAdd(&scnt[bb], 1);
            }
        }
    }
    __syncthreads();

    // exclusive scan of scnt[0..NBK-1]: thread t owns 2 consecutive buckets
    int c0 = scnt[t * 2], c1 = scnt[t * 2 + 1];
    sred2[t] = c0 + c1;
    __syncthreads();
    int sv = sred2[t];
    for (int off = 1; off < 256; off <<= 1) {
        int x = (t >= off) ? sred2[t - off] : 0;
        __syncthreads();
        sred2[t] += x;
        __syncthreads();
    }
    int excl = sred2[t] - sv;
    sstart[t * 2]     = excl;
    sstart[t * 2 + 1] = excl + c0;
    __syncthreads();

    // reserve global space: one atomic per non-empty bucket (padded cursors)
    for (int i = t; i < NBK; i += 256) {
        int c = scnt[i];
        if (c) sgbase[i] = atomicAdd(&bcursor[i * 16], c);
    }
    __syncthreads();

    // place edges into staged slots (dense: sstart[b] + rank)
    #pragma unroll
    for (int k = 0; k < 4; k++) {
        int i2 = base2 + k * 256 + t;
        int e0 = i2 * 2;
        if (e0 < E) {
            int slot = sstart[b0[k]] + r0[k];
            sdat[slot] = p0[k]; sbkt[slot] = (unsigned short)b0[k];
            if (e0 + 1 < E) {
                slot = sstart[b1[k]] + r1[k];
                sdat[slot] = p1[k]; sbkt[slot] = (unsigned short)b1[k];
            }
        }
    }
    __syncthreads();

    // flush: thread-linear over staged slots -> contiguous runs per bucket
    int tc = E - base2 * 2; if (tc > 2048) tc = 2048;
    #pragma unroll
    for (int k = 0; k < 8; k++) {
        int i = k * 256 + t;
        if (i < tc) {
            int bb = sbkt[i];
            int pos = sgbase[bb] + (i - sstart[bb]);
            if (pos < (bb + 1) * CAP) payload[pos] = sdat[i];
        }
    }
}

// ---------------------------------------------------------------------------
// Per-bucket: counting-sort payload by localdst in LDS (scalar int atomics
// only), then register-accumulate reduce wave-per-node (batch ds_read +
// __shfl distribution + 4-way unrolled gathers). No wave64 LDS f32 atomics.
// ---------------------------------------------------------------------------
__global__ __launch_bounds__(512) void k_sortred(
    const float* __restrict__ nf,
    const int* __restrict__ bcursor,
    const int* __restrict__ payload,
    const float* __restrict__ embsum,
    const float* __restrict__ epsp,
    float* __restrict__ h, int N)
{
    __shared__ float sE[60 * D];     // 15360 B
    __shared__ int   sp[CAP];        // 16384 B  raw bucket payload
    __shared__ int   sq[CAP];        // 16384 B  sorted by localdst
    __shared__ int   scn[R + 1];     // node start offsets
    __shared__ int   scur[R];        // scatter cursors
    __shared__ int   sscan[256];     // scan workspace

    int tid = threadIdx.x;
    int b = blockIdx.x;
    int n0 = b * R;

    for (int i = tid; i < 60 * D; i += 512) sE[i] = embsum[i];
    if (tid <= R) scn[tid] = 0;
    __syncthreads();

    int js = b * CAP;
    int cnt = bcursor[b * 16] - js;
    if (cnt > CAP) cnt = CAP;
    if (cnt < 0) cnt = 0;

    // load + per-node count (scalar int LDS atomics; counts at scn[ld+1])
    for (int i = tid; i < cnt; i += 512) {
        int u = payload[js + i];
        sp[i] = u;
        atomicAdd(&scn[((unsigned)u >> 23) + 1], 1);
    }
    __syncthreads();

    // inclusive scan over 256 entries (R+1=197 live) -> scn[k] = start of node k
    if (tid < 256) sscan[tid] = (tid <= R) ? scn[tid] : 0;
    __syncthreads();
    for (int off = 1; off < 256; off <<= 1) {
        int x = 0;
        if (tid < 256 && tid >= off) x = sscan[tid - off];
        __syncthreads();
        if (tid < 256) sscan[tid] += x;
        __syncthreads();
    }
    if (tid <= R) {
        scn[tid] = sscan[tid];
        if (tid < R) scur[tid] = sscan[tid];
    }
    __syncthreads();

    // scatter into sorted order (scalar int LDS atomics on cursors)
    for (int i = tid; i < cnt; i += 512) {
        int u = sp[i];
        int pos = atomicAdd(&scur[(unsigned)u >> 23], 1);
        sq[pos] = u;
    }
    __syncthreads();

    // wave-per-node register-accumulate reduce
    int w = tid >> 6, l = tid & 63;
    float epsv = 1.0f + epsp[0];
    for (int r = w; r < R; r += 8) {
        int n = n0 + r;
        if (n >= N) break;
        int st = scn[r], en = scn[r + 1];
        float acc = 0.0f;
        for (int jb = st; jb < en; jb += 64) {
            int u = (jb + l < en) ? sq[jb + l] : 0;   // LDS batch, stride-1
            int m = en - jb; if (m > 64) m = 64;
            int t = 0;
            for (; t + 4 <= m; t += 4) {
                int a0 = __shfl(u, t + 0);
                int a1 = __shfl(u, t + 1);
                int a2 = __shfl(u, t + 2);
                int a3 = __shfl(u, t + 3);
                float x0 = nf[(size_t)(a0 & 0x1FFFF) * D + l];
                float x1 = nf[(size_t)(a1 & 0x1FFFF) * D + l];
                float x2 = nf[(size_t)(a2 & 0x1FFFF) * D + l];
                float x3 = nf[(size_t)(a3 & 0x1FFFF) * D + l];
                float e0 = sE[((a0 >> 17) & 63) * D + l];
                float e1 = sE[((a1 >> 17) & 63) * D + l];
                float e2 = sE[((a2 >> 17) & 63) * D + l];
                float e3 = sE[((a3 >> 17) & 63) * D + l];
                acc += fmaxf(x0 + e0, 0.0f) + fmaxf(x1 + e1, 0.0f)
                     + fmaxf(x2 + e2, 0.0f) + fmaxf(x3 + e3, 0.0f);
            }
            for (; t < m; t++) {
                int a = __shfl(u, t);
                acc += fmaxf(nf[(size_t)(a & 0x1FFFF) * D + l]
                             + sE[((a >> 17) & 63) * D + l], 0.0f);
            }
        }
        h[(size_t)n * D + l] = fmaf(epsv, nf[(size_t)n * D + l], acc);
    }
}

// ---------------------------------------------------------------------------
// BN stats, syrk-style: per-block register-accumulated partials of
// M = sum_n h_n h_n^T (64x64, 16x16 threads x 4x4 regs) and s = sum_n h_n.
// ---------------------------------------------------------------------------
__global__ __launch_bounds__(256) void k_stats(
    const float* __restrict__ h,
    float* __restrict__ pM,     // [grid][4160]: M (4096) then s (64)
    int N, int tiles)
{
    __shared__ float sH[64 * 68];   // 17408 B
    __shared__ float sred[4 * 64];
    int tid = threadIdx.x;
    int iB = tid >> 4, jB = tid & 15;
    int rg = tid >> 6, lc = tid & 63;

    float M[4][4];
    #pragma unroll
    for (int a = 0; a < 4; a++)
        #pragma unroll
        for (int b = 0; b < 4; b++) M[a][b] = 0.0f;
    float sp = 0.0f;

    for (int t = blockIdx.x; t < tiles; t += gridDim.x) {
        int row0 = t * 64;
        __syncthreads();
        {
            int r = tid >> 2, c16 = (tid & 3) * 16;
            int gr = row0 + r;
            float* dp = &sH[r * 68 + c16];
            if (gr < N) {
                const float4* hr = (const float4*)(h + (size_t)gr * D + c16);
                #pragma unroll
                for (int m2 = 0; m2 < 4; m2++) ((float4*)dp)[m2] = hr[m2];
            } else {
                #pragma unroll
                for (int m2 = 0; m2 < 16; m2++) dp[m2] = 0.0f;
            }
        }
        __syncthreads();

        #pragma unroll 8
        for (int n2 = 0; n2 < 64; n2++) {
            float4 a = *(const float4*)&sH[n2 * 68 + iB * 4];
            float4 b = *(const float4*)&sH[n2 * 68 + jB * 4];
            M[0][0] = fmaf(a.x, b.x, M[0][0]);
            M[0][1] = fmaf(a.x, b.y, M[0][1]);
            M[0][2] = fmaf(a.x, b.z, M[0][2]);
            M[0][3] = fmaf(a.x, b.w, M[0][3]);
            M[1][0] = fmaf(a.y, b.x, M[1][0]);
            M[1][1] = fmaf(a.y, b.y, M[1][1]);
            M[1][2] = fmaf(a.y, b.z, M[1][2]);
            M[1][3] = fmaf(a.y, b.w, M[1][3]);
            M[2][0] = fmaf(a.z, b.x, M[2][0]);
            M[2][1] = fmaf(a.z, b.y, M[2][1]);
            M[2][2] = fmaf(a.z, b.z, M[2][2]);
            M[2][3] = fmaf(a.z, b.w, M[2][3]);
            M[3][0] = fmaf(a.w, b.x, M[3][0]);
            M[3][1] = fmaf(a.w, b.y, M[3][1]);
            M[3][2] = fmaf(a.w, b.z, M[3][2]);
            M[3][3] = fmaf(a.w, b.w, M[3][3]);
        }
        #pragma unroll
        for (int r2 = 0; r2 < 16; r2++)
            sp += sH[(rg * 16 + r2) * 68 + lc];
    }

    float* P = pM + (size_t)blockIdx.x * 4160;
    #pragma unroll
    for (int a = 0; a < 4; a++)
        #pragma unroll
        for (int b = 0; b < 4; b++)
            P[(iB * 4 + a) * 64 + jB * 4 + b] = M[a][b];
    sred[rg * 64 + lc] = sp;
    __syncthreads();
    if (tid < 64)
        P[4096 + tid] = sred[tid] + sred[64 + tid] + sred[128 + tid] + sred[192 + tid];
}

// Reduce partials over blocks; pre-normalize by 1/N.
// 65 blocks x 256 threads: block owns 64 consecutive elements; threads
// (eq, bq) sum partials b = bq..nblk step 4 with 4 independent accumulators;
// reads coalesced 256B/wave; LDS-reduce the 4 bq groups.
__global__ __launch_bounds__(256) void k_redM(
    const float* __restrict__ pM, int nblk,
    float* __restrict__ Mbar, float invN)
{
    __shared__ float sred[256];
    int tid = threadIdx.x;
    int eq = tid & 63, bq = tid >> 6;
    int e = blockIdx.x * 64 + eq;

    float s0 = 0.0f, s1 = 0.0f, s2 = 0.0f, s3 = 0.0f;
    if (e < 4160) {
        int b = bq;
        for (; b + 12 < nblk; b += 16) {
            s0 += pM[(size_t)(b +  0) * 4160 + e];
            s1 += pM[(size_t)(b +  4) * 4160 + e];
            s2 += pM[(size_t)(b +  8) * 4160 + e];
            s3 += pM[(size_t)(b + 12) * 4160 + e];
        }
        for (; b < nblk; b += 4) s0 += pM[(size_t)b * 4160 + e];
    }
    sred[tid] = (s0 + s1) + (s2 + s3);
    __syncthreads();
    if (tid < 64 && e < 4160)
        Mbar[e] = (sred[tid] + sred[64 + tid] + sred[128 + tid] + sred[192 + tid]) * invN;
}

// Per-channel BN scale/shift: var_c = w^T Mbar w - (w.sbar)^2, mean = w.sbar+b1.
__global__ void k_bn(
    const float* __restrict__ Mbar,   // [4160]: M (64x64) then sbar (64)
    const float* __restrict__ W1,     // [128,64]
    const float* __restrict__ b1,
    const float* __restrict__ gamma, const float* __restrict__ beta,
    float* __restrict__ ss)
{
    __shared__ float sMb[4160];
    int tid = threadIdx.x;  // 128 threads
    for (int i = tid; i < 4160; i += 128) sMb[i] = Mbar[i];
    __syncthreads();

    int c = tid;
    float w[64];
    #pragma unroll
    for (int k = 0; k < 64; k++) w[k] = W1[c * D + k];

    float d = 0.0f;
    #pragma unroll
    for (int k = 0; k < 64; k++) d = fmaf(w[k], sMb[4096 + k], d);

    float Q = 0.0f;
    for (int k = 0; k < 64; k++) {
        float tk = 0.0f;
        #pragma unroll
        for (int j = 0; j < 64; j++) tk = fmaf(sMb[k * 64 + j], w[j], tk);
        Q = fmaf(w[k], tk, Q);
    }

    float var  = fmaxf(Q - d * d, 0.0f);
    float mean = d + b1[c];
    float sc   = gamma[c] * rsqrtf(var + 1e-5f);
    ss[c]       = sc;
    ss[128 + c] = beta[c] - mean * sc;
}

// ---------------------------------------------------------------------------
// GEMM2: persistent blocks, 32-row tiles.
// LDS = AB 16K + W1t 32K + W2t 32K = 80 KB -> 2 blocks/CU = 8 waves/CU.
// ---------------------------------------------------------------------------
__global__ __launch_bounds__(256) void k_gemm2(
    const float* __restrict__ h,
    const float* __restrict__ W1,    // [128,64]
    const float* __restrict__ b1,    // [128]
    const float* __restrict__ ss,    // scale/shift [256]
    const float* __restrict__ W2,    // [64,128]
    const float* __restrict__ b2v,   // [64]
    float* __restrict__ out,         // [N,64]
    int N, int tiles)
{
    __shared__ float AB[32 * 128];
    __shared__ float W1t[64 * 128];
    __shared__ float W2t[128 * 64];

    int tid = threadIdx.x;
    int ty = tid >> 5, tx = tid & 31;

    {   // stage W1^T: W1t[k][c]
        int c  = tid >> 1;
        int k0 = (tid & 1) * 32;
        const float4* wr = (const float4*)(W1 + c * D + k0);
        #pragma unroll
        for (int q = 0; q < 8; q++) {
            float4 u = wr[q];
            int k = k0 + q * 4;
            W1t[(k + 0) * 128 + c] = u.x;
            W1t[(k + 1) * 128 + c] = u.y;
            W1t[(k + 2) * 128 + c] = u.z;
            W1t[(k + 3) * 128 + c] = u.w;
        }
    }
    {   // stage W2^T: W2t[k][j]
        int j  = tid >> 2;
        int k0 = (tid & 3) * 32;
        const float4* wr = (const float4*)(W2 + j * D2 + k0);
        #pragma unroll
        for (int q = 0; q < 8; q++) {
            float4 u = wr[q];
            int k = k0 + q * 4;
            W2t[(k + 0) * 64 + j] = u.x;
            W2t[(k + 1) * 64 + j] = u.y;
            W2t[(k + 2) * 64 + j] = u.z;
            W2t[(k + 3) * 64 + j] = u.w;
        }
    }

    float bb0 = b1[tx * 4 + 0];
    float bb1 = b1[tx * 4 + 1];
    float bb2 = b1[tx * 4 + 2];
    float bb3 = b1[tx * 4 + 3];
    float4 scv = *(const float4*)&ss[tx * 4];
    float4 shv = *(const float4*)&ss[128 + tx * 4];
    float ob0 = b2v[tx * 2 + 0];
    float ob1 = b2v[tx * 2 + 1];

    for (int t = blockIdx.x; t < tiles; t += gridDim.x) {
        int row0 = t * 32;
        __syncthreads();
        {   // phase A: stage h tile, 32 rows x 64 cols (8 floats/thread)
            int r  = tid >> 3;
            int c8 = (tid & 7) * 8;
            int gr = row0 + r;
            float* dstp = &AB[r * 128 + c8];
            if (gr < N) {
                const float4* hrow = (const float4*)(h + (size_t)gr * D + c8);
                ((float4*)dstp)[0] = hrow[0];
                ((float4*)dstp)[1] = hrow[1];
            } else {
                #pragma unroll
                for (int m = 0; m < 8; m++) dstp[m] = 0.0f;
            }
        }
        __syncthreads();

        float acc[4][4];
        #pragma unroll
        for (int i = 0; i < 4; i++)
            #pragma unroll
            for (int j = 0; j < 4; j++) acc[i][j] = 0.0f;

        #pragma unroll 4
        for (int k4 = 0; k4 < 16; k4++) {
            float4 w0 = *(const float4*)&W1t[(k4 * 4 + 0) * 128 + tx * 4];
            float4 w1 = *(const float4*)&W1t[(k4 * 4 + 1) * 128 + tx * 4];
            float4 w2 = *(const float4*)&W1t[(k4 * 4 + 2) * 128 + tx * 4];
            float4 w3 = *(const float4*)&W1t[(k4 * 4 + 3) * 128 + tx * 4];
            #pragma unroll
            for (int i = 0; i < 4; i++) {
                float4 a = *(const float4*)&AB[(ty * 4 + i) * 128 + k4 * 4];
                acc[i][0] = fmaf(a.x, w0.x, acc[i][0]);
                acc[i][1] = fmaf(a.x, w0.y, acc[i][1]);
                acc[i][2] = fmaf(a.x, w0.z, acc[i][2]);
                acc[i][3] = fmaf(a.x, w0.w, acc[i][3]);
                acc[i][0] = fmaf(a.y, w1.x, acc[i][0]);
                acc[i][1] = fmaf(a.y, w1.y, acc[i][1]);
                acc[i][2] = fmaf(a.y, w1.z, acc[i][2]);
                acc[i][3] = fmaf(a.y, w1.w, acc[i][3]);
                acc[i][0] = fmaf(a.z, w2.x, acc[i][0]);
                acc[i][1] = fmaf(a.z, w2.y, acc[i][1]);
                acc[i][2] = fmaf(a.z, w2.z, acc[i][2]);
                acc[i][3] = fmaf(a.z, w2.w, acc[i][3]);
                acc[i][0] = fmaf(a.w, w3.x, acc[i][0]);
                acc[i][1] = fmaf(a.w, w3.y, acc[i][1]);
                acc[i][2] = fmaf(a.w, w3.z, acc[i][2]);
                acc[i][3] = fmaf(a.w, w3.w, acc[i][3]);
            }
        }
        __syncthreads();

        #pragma unroll
        for (int i = 0; i < 4; i++) {
            float g0 = fmaxf(fmaf(acc[i][0] + bb0, scv.x, shv.x), 0.0f);
            float g1 = fmaxf(fmaf(acc[i][1] + bb1, scv.y, shv.y), 0.0f);
            float g2 = fmaxf(fmaf(acc[i][2] + bb2, scv.z, shv.z), 0.0f);
            float g3 = fmaxf(fmaf(acc[i][3] + bb3, scv.w, shv.w), 0.0f);
            *(float4*)&AB[(ty * 4 + i) * 128 + tx * 4] = make_float4(g0, g1, g2, g3);
        }
        __syncthreads();

        float acc2[4][2];
        #pragma unroll
        for (int i = 0; i < 4; i++) { acc2[i][0] = 0.0f; acc2[i][1] = 0.0f; }

        #pragma unroll 4
        for (int k4 = 0; k4 < 32; k4++) {
            float2 u0 = *(const float2*)&W2t[(k4 * 4 + 0) * 64 + tx * 2];
            float2 u1 = *(const float2*)&W2t[(k4 * 4 + 1) * 64 + tx * 2];
            float2 u2 = *(const float2*)&W2t[(k4 * 4 + 2) * 64 + tx * 2];
            float2 u3 = *(const float2*)&W2t[(k4 * 4 + 3) * 64 + tx * 2];
            #pragma unroll
            for (int i = 0; i < 4; i++) {
                float4 b = *(const float4*)&AB[(ty * 4 + i) * 128 + k4 * 4];
                acc2[i][0] = fmaf(b.x, u0.x, acc2[i][0]);
                acc2[i][1] = fmaf(b.x, u0.y, acc2[i][1]);
                acc2[i][0] = fmaf(b.y, u1.x, acc2[i][0]);
                acc2[i][1] = fmaf(b.y, u1.y, acc2[i][1]);
                acc2[i][0] = fmaf(b.z, u2.x, acc2[i][0]);
                acc2[i][1] = fmaf(b.z, u2.y, acc2[i][1]);
                acc2[i][0] = fmaf(b.w, u3.x, acc2[i][0]);
                acc2[i][1] = fmaf(b.w, u3.y, acc2[i][1]);
            }
        }

        #pragma unroll
        for (int i = 0; i < 4; i++) {
            int gr = row0 + ty * 4 + i;
            if (gr < N) {
                float2 pk = make_float2(acc2[i][0] + ob0, acc2[i][1] + ob1);
                ((float2*)out)[(size_t)gr * 32 + tx] = pk;
            }
        }
    }
}

// ---------------------------------------------------------------------------
extern "C" void kernel_launch(void* const* d_in, const int* in_sizes, int n_in,
                              void* d_out, int out_size, void* d_ws, size_t ws_size,
                              hipStream_t stream)
{
    const float* nf    = (const float*)d_in[0];
    const int*   ef    = (const int*)d_in[1];
    const int*   ei    = (const int*)d_in[2];
    const float* epsp  = (const float*)d_in[5];
    const float* be0   = (const float*)d_in[6];
    const float* be1   = (const float*)d_in[7];
    const float* be2   = (const float*)d_in[8];
    const float* W1    = (const float*)d_in[9];
    const float* b1    = (const float*)d_in[10];
    const float* gamma = (const float*)d_in[11];
    const float* beta  = (const float*)d_in[12];
    const float* W2    = (const float*)d_in[13];
    const float* b2v   = (const float*)d_in[14];
    float*       out   = (float*)d_out;

    int N = in_sizes[0] / D;    // 100000
    int E = in_sizes[1] / 3;    // 1600000

    int gS = 512;                         // k_stats blocks (2 blocks/CU)
    int tilesS = (N + 63) / 64;           // 1563
    int tiles2 = (N + 31) / 32;           // 3125 (32-row tiles)
    int g2 = 512;                         // 2 blocks/CU (80 KB LDS)

    // workspace layout (4-byte elements); pM aliases payload (payload is
    // dead after k_sortred, pM written by k_stats afterwards)
    float* h       = (float*)d_ws;                    // N*64
    float* Mbar    = h + (size_t)N * D;               // 4160
    float* ss      = Mbar + 4160;                     // 256
    float* embsum  = ss + 256;                        // 60*64
    int*   bcursor = (int*)(embsum + 60 * D);         // NBK*16 (line-padded)
    int*   payload = bcursor + NBK * 16;              // NBK*CAP = 2,097,152
    float* pM      = (float*)payload;                 // gS*4160 = 2,129,920

    k_init<<<2, 256, 0, stream>>>(bcursor);
    k_embsum<<<60, 64, 0, stream>>>(be0, be1, be2, embsum);

    int E2 = (E + 1) / 2;
    int gP = (E2 + 1023) / 1024;          // 782 tiles of 2048 edges
    k_part<<<gP, 256, 0, stream>>>(ei, ef, bcursor, payload, E);

    k_sortred<<<NBK, 512, 0, stream>>>(nf, bcursor, payload, embsum, epsp, h, N);

    k_stats<<<gS, 256, 0, stream>>>(h, pM, N, tilesS);
    k_redM<<<65, 256, 0, stream>>>(pM, gS, Mbar, 1.0f / (float)N);
    k_bn<<<1, 128, 0, stream>>>(Mbar, W1, b1, gamma, beta, ss);

    k_gemm2<<<g2, 256, 0, stream>>>(h, W1, b1, ss, W2, b2v, out, N, tiles2);
}

// Round 6
// 370.122 us; speedup vs baseline: 1.3259x; 1.0211x over previous
//
#include <hip/hip_runtime.h>
#include <stdint.h>

#define D   64
#define D2  128
#define R   196          // nodes per bucket  (512*196 = 100352 >= N)
#define NBK 512          // buckets
#define CAP 4224         // payload slots per bucket (mean 3125; also >= 4160
                         // so the per-block M/s partial record fits in-place)

// ---------------------------------------------------------------------------
// Embedding-sum table + cursor init fused: blocks 0..59 build embsum,
// blocks 60..67 init the line-padded bump allocators.
// ---------------------------------------------------------------------------
__global__ void k_embsum(
    const float* __restrict__ be0, const float* __restrict__ be1,
    const float* __restrict__ be2, float* __restrict__ embsum,
    int* __restrict__ bcursor)
{
    int c = blockIdx.x;
    int t = threadIdx.x;     // 0..63
    if (c < 60) {
        int f0 = c / 12;
        int r  = c % 12;
        int f1 = r / 2;
        int f2 = r % 2;
        embsum[c * D + t] = be0[f0 * D + t] + be1[f1 * D + t] + be2[f2 * D + t];
    } else {
        int i = (c - 60) * 64 + t;
        if (i < NBK) bcursor[i * 16] = i * CAP;
    }
}

// ---------------------------------------------------------------------------
// Bucket partition: tile of 2048 edges per block, LDS-staged so the global
// payload writes are contiguous runs (avg 4 edges = 16B per bucket per tile).
// payload word: src | (code<<17) | (localdst<<23)   (17+6+8 = 31 bits)
// ---------------------------------------------------------------------------
__global__ __launch_bounds__(256) void k_part(
    const int* __restrict__ ei, const int* __restrict__ ef,
    int* __restrict__ bcursor, int* __restrict__ payload, int E)
{
    __shared__ int scnt[NBK];            // per-tile bucket counts (2 KB)
    __shared__ int sstart[NBK];          // exclusive scan of scnt (2 KB)
    __shared__ int sgbase[NBK];          // reserved global base per bucket (2 KB)
    __shared__ int sdat[2048];           // staged payload words (8 KB)
    __shared__ unsigned short sbkt[2048];// bucket of each staged slot (4 KB)
    __shared__ int sred2[256];           // block-scan partials (1 KB)

    int t = threadIdx.x;
    for (int i = t; i < NBK; i += 256) scnt[i] = 0;
    __syncthreads();

    int base2 = blockIdx.x * 1024;       // pair index base (2 edges/pair)

    int b0[4], p0[4], r0[4];
    int b1[4], p1[4], r1[4];

    #pragma unroll
    for (int k = 0; k < 4; k++) {
        int i2 = base2 + k * 256 + t;
        int e0 = i2 * 2;
        if (e0 < E) {
            int2 d  = ((const int2*)ei)[i2];
            int2 s  = ((const int2*)(ei + E))[i2];
            int2 q0 = ((const int2*)ef)[3 * i2 + 0];
            int2 q1 = ((const int2*)ef)[3 * i2 + 1];
            int2 q2 = ((const int2*)ef)[3 * i2 + 2];
            {
                int bb = d.x / R; if (bb > NBK - 1) bb = NBK - 1;
                int ld = d.x - bb * R;
                int code = q0.x * 12 + q0.y * 2 + q1.x;
                b0[k] = bb;
                p0[k] = s.x | (code << 17) | (ld << 23);
                r0[k] = atomicAdd(&scnt[bb], 1);
            }
            if (e0 + 1 < E) {
                int bb = d.y / R; if (bb > NBK - 1) bb = NBK - 1;
                int ld = d.y - bb * R;
                int code = q1.y * 12 + q2.x * 2 + q2.y;
                b1[k] = bb;
                p1[k] = s.y | (code << 17) | (ld << 23);
                r1[k] = atomicAdd(&scnt[bb], 1);
            }
        }
    }
    __syncthreads();

    // exclusive scan of scnt[0..NBK-1]: thread t owns 2 consecutive buckets
    int c0 = scnt[t * 2], c1 = scnt[t * 2 + 1];
    sred2[t] = c0 + c1;
    __syncthreads();
    int sv = sred2[t];
    for (int off = 1; off < 256; off <<= 1) {
        int x = (t >= off) ? sred2[t - off] : 0;
        __syncthreads();
        sred2[t] += x;
        __syncthreads();
    }
    int excl = sred2[t] - sv;
    sstart[t * 2]     = excl;
    sstart[t * 2 + 1] = excl + c0;
    __syncthreads();

    // reserve global space: one atomic per non-empty bucket (padded cursors)
    for (int i = t; i < NBK; i += 256) {
        int c = scnt[i];
        if (c) sgbase[i] = atomicAdd(&bcursor[i * 16], c);
    }
    __syncthreads();

    // place edges into staged slots (dense: sstart[b] + rank)
    #pragma unroll
    for (int k = 0; k < 4; k++) {
        int i2 = base2 + k * 256 + t;
        int e0 = i2 * 2;
        if (e0 < E) {
            int slot = sstart[b0[k]] + r0[k];
            sdat[slot] = p0[k]; sbkt[slot] = (unsigned short)b0[k];
            if (e0 + 1 < E) {
                slot = sstart[b1[k]] + r1[k];
                sdat[slot] = p1[k]; sbkt[slot] = (unsigned short)b1[k];
            }
        }
    }
    __syncthreads();

    // flush: thread-linear over staged slots -> contiguous runs per bucket
    int tc = E - base2 * 2; if (tc > 2048) tc = 2048;
    #pragma unroll
    for (int k = 0; k < 8; k++) {
        int i = k * 256 + t;
        if (i < tc) {
            int bb = sbkt[i];
            int pos = sgbase[bb] + (i - sstart[bb]);
            if (pos < (bb + 1) * CAP) payload[pos] = sdat[i];
        }
    }
}

// ---------------------------------------------------------------------------
// Per-bucket, 3 phases in one kernel (LDS manually unioned):
//  1) counting-sort payload by localdst (scalar int LDS atomics only) +
//     register-accumulate reduce wave-per-node -> h  (round-3 structure)
//  2) re-stage own h tile (L2-hot, just written by this CU) into LDS
//  3) syrk partial M = sum h h^T (16x16 thr x 4x4 regs) + column-sum s,
//     written in-place into this bucket's (now dead) payload region.
// Eliminates k_stats' 25.6 MB HBM re-read + a kernel launch.
// ---------------------------------------------------------------------------
#define SME   0                              // sE    60*64 f  (15360 B)
#define SMP   15360                          // sp    CAP  i   (16896 B)
#define SMQ   32256                          // sq    CAP  i   (16896 B)
#define SMC   49152                          // scn   R+1  i   (788 B)
#define SMU   49940                          // scur  R    i   (784 B)
#define SMS   50724                          // sscan 256  i   (1024 B)
#define SMEM_BYTES 53376                     // phase2 hbuf 196*68 f = 53312 B

__global__ __launch_bounds__(512) void k_sortred(
    const float* __restrict__ nf,
    const int* __restrict__ bcursor,
    int* __restrict__ payload,
    const float* __restrict__ embsum,
    const float* __restrict__ epsp,
    float* __restrict__ h, int N)
{
    __shared__ __align__(16) char smem[SMEM_BYTES];
    float* sE    = (float*)(smem + SME);
    int*   sp    = (int*)(smem + SMP);
    int*   sq    = (int*)(smem + SMQ);
    int*   scn   = (int*)(smem + SMC);
    int*   scur  = (int*)(smem + SMU);
    int*   sscan = (int*)(smem + SMS);
    float* hbuf  = (float*)smem;             // phase 2 overlay [196][68]

    int tid = threadIdx.x;
    int b = blockIdx.x;
    int n0 = b * R;

    for (int i = tid; i < 60 * D; i += 512) sE[i] = embsum[i];
    if (tid <= R) scn[tid] = 0;
    __syncthreads();

    int js = b * CAP;
    int cnt = bcursor[b * 16] - js;
    if (cnt > CAP) cnt = CAP;
    if (cnt < 0) cnt = 0;

    // load + per-node count (scalar int LDS atomics; counts at scn[ld+1])
    for (int i = tid; i < cnt; i += 512) {
        int u = payload[js + i];
        sp[i] = u;
        atomicAdd(&scn[((unsigned)u >> 23) + 1], 1);
    }
    __syncthreads();

    // inclusive scan over 256 entries (R+1=197 live)
    if (tid < 256) sscan[tid] = (tid <= R) ? scn[tid] : 0;
    __syncthreads();
    for (int off = 1; off < 256; off <<= 1) {
        int x = 0;
        if (tid < 256 && tid >= off) x = sscan[tid - off];
        __syncthreads();
        if (tid < 256) sscan[tid] += x;
        __syncthreads();
    }
    if (tid <= R) {
        scn[tid] = sscan[tid];
        if (tid < R) scur[tid] = sscan[tid];
    }
    __syncthreads();

    // scatter into sorted order
    for (int i = tid; i < cnt; i += 512) {
        int u = sp[i];
        int pos = atomicAdd(&scur[(unsigned)u >> 23], 1);
        sq[pos] = u;
    }
    __syncthreads();

    // wave-per-node register-accumulate reduce
    int w = tid >> 6, l = tid & 63;
    float epsv = 1.0f + epsp[0];
    for (int r = w; r < R; r += 8) {
        int n = n0 + r;
        if (n >= N) break;
        int st = scn[r], en = scn[r + 1];
        float acc = 0.0f;
        for (int jb = st; jb < en; jb += 64) {
            int u = (jb + l < en) ? sq[jb + l] : 0;
            int m = en - jb; if (m > 64) m = 64;
            int t = 0;
            for (; t + 4 <= m; t += 4) {
                int a0 = __shfl(u, t + 0);
                int a1 = __shfl(u, t + 1);
                int a2 = __shfl(u, t + 2);
                int a3 = __shfl(u, t + 3);
                float x0 = nf[(size_t)(a0 & 0x1FFFF) * D + l];
                float x1 = nf[(size_t)(a1 & 0x1FFFF) * D + l];
                float x2 = nf[(size_t)(a2 & 0x1FFFF) * D + l];
                float x3 = nf[(size_t)(a3 & 0x1FFFF) * D + l];
                float e0 = sE[((a0 >> 17) & 63) * D + l];
                float e1 = sE[((a1 >> 17) & 63) * D + l];
                float e2 = sE[((a2 >> 17) & 63) * D + l];
                float e3 = sE[((a3 >> 17) & 63) * D + l];
                acc += fmaxf(x0 + e0, 0.0f) + fmaxf(x1 + e1, 0.0f)
                     + fmaxf(x2 + e2, 0.0f) + fmaxf(x3 + e3, 0.0f);
            }
            for (; t < m; t++) {
                int a = __shfl(u, t);
                acc += fmaxf(nf[(size_t)(a & 0x1FFFF) * D + l]
                             + sE[((a >> 17) & 63) * D + l], 0.0f);
            }
        }
        h[(size_t)n * D + l] = fmaf(epsv, nf[(size_t)n * D + l], acc);
    }
    __syncthreads();   // all phase-1 LDS reads done; smem reusable

    // phase 2: stage own h tile (L2-hot) into hbuf[196][68]
    for (int idx = tid; idx < R * 16; idx += 512) {
        int row = idx >> 4, q = idx & 15;
        int n = n0 + row;
        float4 v = make_float4(0.0f, 0.0f, 0.0f, 0.0f);
        if (n < N) v = *(const float4*)&h[(size_t)n * D + q * 4];
        *(float4*)&hbuf[row * 68 + q * 4] = v;
    }
    __syncthreads();

    // phase 3: partial M (tid<256) + column-sum s (wave 4), in-place into
    // this bucket's payload region: P[0..4095]=M, P[4096..4159]=s
    float* P = (float*)(payload + (size_t)b * CAP);
    if (tid < 256) {
        int iB = tid >> 4, jB = tid & 15;
        float M[4][4];
        #pragma unroll
        for (int a = 0; a < 4; a++)
            #pragma unroll
            for (int c = 0; c < 4; c++) M[a][c] = 0.0f;
        #pragma unroll 4
        for (int n2 = 0; n2 < R; n2++) {
            float4 a = *(const float4*)&hbuf[n2 * 68 + iB * 4];
            float4 c = *(const float4*)&hbuf[n2 * 68 + jB * 4];
            M[0][0] = fmaf(a.x, c.x, M[0][0]);
            M[0][1] = fmaf(a.x, c.y, M[0][1]);
            M[0][2] = fmaf(a.x, c.z, M[0][2]);
            M[0][3] = fmaf(a.x, c.w, M[0][3]);
            M[1][0] = fmaf(a.y, c.x, M[1][0]);
            M[1][1] = fmaf(a.y, c.y, M[1][1]);
            M[1][2] = fmaf(a.y, c.z, M[1][2]);
            M[1][3] = fmaf(a.y, c.w, M[1][3]);
            M[2][0] = fmaf(a.z, c.x, M[2][0]);
            M[2][1] = fmaf(a.z, c.y, M[2][1]);
            M[2][2] = fmaf(a.z, c.z, M[2][2]);
            M[2][3] = fmaf(a.z, c.w, M[2][3]);
            M[3][0] = fmaf(a.w, c.x, M[3][0]);
            M[3][1] = fmaf(a.w, c.y, M[3][1]);
            M[3][2] = fmaf(a.w, c.z, M[3][2]);
            M[3][3] = fmaf(a.w, c.w, M[3][3]);
        }
        #pragma unroll
        for (int a = 0; a < 4; a++)
            #pragma unroll
            for (int c = 0; c < 4; c++)
                P[(iB * 4 + a) * 64 + jB * 4 + c] = M[a][c];
    } else if (tid < 320) {
        int lc = tid - 256;
        float s = 0.0f;
        for (int r2 = 0; r2 < R; r2++) s += hbuf[r2 * 68 + lc];
        P[4096 + lc] = s;
    }
}

// Reduce per-bucket partials (stride CAP); pre-normalize by 1/N.
// 65 blocks x 256 threads, 4 independent accumulators, coalesced reads.
__global__ __launch_bounds__(256) void k_redM(
    const float* __restrict__ pM, int nblk,
    float* __restrict__ Mbar, float invN)
{
    __shared__ float sred[256];
    int tid = threadIdx.x;
    int eq = tid & 63, bq = tid >> 6;
    int e = blockIdx.x * 64 + eq;

    float s0 = 0.0f, s1 = 0.0f, s2 = 0.0f, s3 = 0.0f;
    if (e < 4160) {
        int b = bq;
        for (; b + 12 < nblk; b += 16) {
            s0 += pM[(size_t)(b +  0) * CAP + e];
            s1 += pM[(size_t)(b +  4) * CAP + e];
            s2 += pM[(size_t)(b +  8) * CAP + e];
            s3 += pM[(size_t)(b + 12) * CAP + e];
        }
        for (; b < nblk; b += 4) s0 += pM[(size_t)b * CAP + e];
    }
    sred[tid] = (s0 + s1) + (s2 + s3);
    __syncthreads();
    if (tid < 64 && e < 4160)
        Mbar[e] = (sred[tid] + sred[64 + tid] + sred[128 + tid] + sred[192 + tid]) * invN;
}

// Per-channel BN scale/shift: var_c = w^T Mbar w - (w.sbar)^2, mean = w.sbar+b1.
__global__ void k_bn(
    const float* __restrict__ Mbar,   // [4160]: M (64x64) then sbar (64)
    const float* __restrict__ W1,     // [128,64]
    const float* __restrict__ b1,
    const float* __restrict__ gamma, const float* __restrict__ beta,
    float* __restrict__ ss)
{
    __shared__ float sMb[4160];
    int tid = threadIdx.x;  // 128 threads
    for (int i = tid; i < 4160; i += 128) sMb[i] = Mbar[i];
    __syncthreads();

    int c = tid;
    float w[64];
    #pragma unroll
    for (int k = 0; k < 64; k++) w[k] = W1[c * D + k];

    float d = 0.0f;
    #pragma unroll
    for (int k = 0; k < 64; k++) d = fmaf(w[k], sMb[4096 + k], d);

    float Q = 0.0f;
    for (int k = 0; k < 64; k++) {
        float tk = 0.0f;
        #pragma unroll
        for (int j = 0; j < 64; j++) tk = fmaf(sMb[k * 64 + j], w[j], tk);
        Q = fmaf(w[k], tk, Q);
    }

    float var  = fmaxf(Q - d * d, 0.0f);
    float mean = d + b1[c];
    float sc   = gamma[c] * rsqrtf(var + 1e-5f);
    ss[c]       = sc;
    ss[128 + c] = beta[c] - mean * sc;
}

// ---------------------------------------------------------------------------
// GEMM2: persistent blocks, 32-row tiles.
// LDS = AB 16K + W1t 32K + W2t 32K = 80 KB -> 2 blocks/CU = 8 waves/CU.
// ---------------------------------------------------------------------------
__global__ __launch_bounds__(256) void k_gemm2(
    const float* __restrict__ h,
    const float* __restrict__ W1,    // [128,64]
    const float* __restrict__ b1,    // [128]
    const float* __restrict__ ss,    // scale/shift [256]
    const float* __restrict__ W2,    // [64,128]
    const float* __restrict__ b2v,   // [64]
    float* __restrict__ out,         // [N,64]
    int N, int tiles)
{
    __shared__ float AB[32 * 128];
    __shared__ float W1t[64 * 128];
    __shared__ float W2t[128 * 64];

    int tid = threadIdx.x;
    int ty = tid >> 5, tx = tid & 31;

    {   // stage W1^T: W1t[k][c]
        int c  = tid >> 1;
        int k0 = (tid & 1) * 32;
        const float4* wr = (const float4*)(W1 + c * D + k0);
        #pragma unroll
        for (int q = 0; q < 8; q++) {
            float4 u = wr[q];
            int k = k0 + q * 4;
            W1t[(k + 0) * 128 + c] = u.x;
            W1t[(k + 1) * 128 + c] = u.y;
            W1t[(k + 2) * 128 + c] = u.z;
            W1t[(k + 3) * 128 + c] = u.w;
        }
    }
    {   // stage W2^T: W2t[k][j]
        int j  = tid >> 2;
        int k0 = (tid & 3) * 32;
        const float4* wr = (const float4*)(W2 + j * D2 + k0);
        #pragma unroll
        for (int q = 0; q < 8; q++) {
            float4 u = wr[q];
            int k = k0 + q * 4;
            W2t[(k + 0) * 64 + j] = u.x;
            W2t[(k + 1) * 64 + j] = u.y;
            W2t[(k + 2) * 64 + j] = u.z;
            W2t[(k + 3) * 64 + j] = u.w;
        }
    }

    float bb0 = b1[tx * 4 + 0];
    float bb1 = b1[tx * 4 + 1];
    float bb2 = b1[tx * 4 + 2];
    float bb3 = b1[tx * 4 + 3];
    float4 scv = *(const float4*)&ss[tx * 4];
    float4 shv = *(const float4*)&ss[128 + tx * 4];
    float ob0 = b2v[tx * 2 + 0];
    float ob1 = b2v[tx * 2 + 1];

    for (int t = blockIdx.x; t < tiles; t += gridDim.x) {
        int row0 = t * 32;
        __syncthreads();
        {   // phase A: stage h tile, 32 rows x 64 cols (8 floats/thread)
            int r  = tid >> 3;
            int c8 = (tid & 7) * 8;
            int gr = row0 + r;
            float* dstp = &AB[r * 128 + c8];
            if (gr < N) {
                const float4* hrow = (const float4*)(h + (size_t)gr * D + c8);
                ((float4*)dstp)[0] = hrow[0];
                ((float4*)dstp)[1] = hrow[1];
            } else {
                #pragma unroll
                for (int m = 0; m < 8; m++) dstp[m] = 0.0f;
            }
        }
        __syncthreads();

        float acc[4][4];
        #pragma unroll
        for (int i = 0; i < 4; i++)
            #pragma unroll
            for (int j = 0; j < 4; j++) acc[i][j] = 0.0f;

        #pragma unroll 4
        for (int k4 = 0; k4 < 16; k4++) {
            float4 w0 = *(const float4*)&W1t[(k4 * 4 + 0) * 128 + tx * 4];
            float4 w1 = *(const float4*)&W1t[(k4 * 4 + 1) * 128 + tx * 4];
            float4 w2 = *(const float4*)&W1t[(k4 * 4 + 2) * 128 + tx * 4];
            float4 w3 = *(const float4*)&W1t[(k4 * 4 + 3) * 128 + tx * 4];
            #pragma unroll
            for (int i = 0; i < 4; i++) {
                float4 a = *(const float4*)&AB[(ty * 4 + i) * 128 + k4 * 4];
                acc[i][0] = fmaf(a.x, w0.x, acc[i][0]);
                acc[i][1] = fmaf(a.x, w0.y, acc[i][1]);
                acc[i][2] = fmaf(a.x, w0.z, acc[i][2]);
                acc[i][3] = fmaf(a.x, w0.w, acc[i][3]);
                acc[i][0] = fmaf(a.y, w1.x, acc[i][0]);
                acc[i][1] = fmaf(a.y, w1.y, acc[i][1]);
                acc[i][2] = fmaf(a.y, w1.z, acc[i][2]);
                acc[i][3] = fmaf(a.y, w1.w, acc[i][3]);
                acc[i][0] = fmaf(a.z, w2.x, acc[i][0]);
                acc[i][1] = fmaf(a.z, w2.y, acc[i][1]);
                acc[i][2] = fmaf(a.z, w2.z, acc[i][2]);
                acc[i][3] = fmaf(a.z, w2.w, acc[i][3]);
                acc[i][0] = fmaf(a.w, w3.x, acc[i][0]);
                acc[i][1] = fmaf(a.w, w3.y, acc[i][1]);
                acc[i][2] = fmaf(a.w, w3.z, acc[i][2]);
                acc[i][3] = fmaf(a.w, w3.w, acc[i][3]);
            }
        }
        __syncthreads();

        #pragma unroll
        for (int i = 0; i < 4; i++) {
            float g0 = fmaxf(fmaf(acc[i][0] + bb0, scv.x, shv.x), 0.0f);
            float g1 = fmaxf(fmaf(acc[i][1] + bb1, scv.y, shv.y), 0.0f);
            float g2 = fmaxf(fmaf(acc[i][2] + bb2, scv.z, shv.z), 0.0f);
            float g3 = fmaxf(fmaf(acc[i][3] + bb3, scv.w, shv.w), 0.0f);
            *(float4*)&AB[(ty * 4 + i) * 128 + tx * 4] = make_float4(g0, g1, g2, g3);
        }
        __syncthreads();

        float acc2[4][2];
        #pragma unroll
        for (int i = 0; i < 4; i++) { acc2[i][0] = 0.0f; acc2[i][1] = 0.0f; }

        #pragma unroll 4
        for (int k4 = 0; k4 < 32; k4++) {
            float2 u0 = *(const float2*)&W2t[(k4 * 4 + 0) * 64 + tx * 2];
            float2 u1 = *(const float2*)&W2t[(k4 * 4 + 1) * 64 + tx * 2];
            float2 u2 = *(const float2*)&W2t[(k4 * 4 + 2) * 64 + tx * 2];
            float2 u3 = *(const float2*)&W2t[(k4 * 4 + 3) * 64 + tx * 2];
            #pragma unroll
            for (int i = 0; i < 4; i++) {
                float4 b = *(const float4*)&AB[(ty * 4 + i) * 128 + k4 * 4];
                acc2[i][0] = fmaf(b.x, u0.x, acc2[i][0]);
                acc2[i][1] = fmaf(b.x, u0.y, acc2[i][1]);
                acc2[i][0] = fmaf(b.y, u1.x, acc2[i][0]);
                acc2[i][1] = fmaf(b.y, u1.y, acc2[i][1]);
                acc2[i][0] = fmaf(b.z, u2.x, acc2[i][0]);
                acc2[i][1] = fmaf(b.z, u2.y, acc2[i][1]);
                acc2[i][0] = fmaf(b.w, u3.x, acc2[i][0]);
                acc2[i][1] = fmaf(b.w, u3.y, acc2[i][1]);
            }
        }

        #pragma unroll
        for (int i = 0; i < 4; i++) {
            int gr = row0 + ty * 4 + i;
            if (gr < N) {
                float2 pk = make_float2(acc2[i][0] + ob0, acc2[i][1] + ob1);
                ((float2*)out)[(size_t)gr * 32 + tx] = pk;
            }
        }
    }
}

// ---------------------------------------------------------------------------
extern "C" void kernel_launch(void* const* d_in, const int* in_sizes, int n_in,
                              void* d_out, int out_size, void* d_ws, size_t ws_size,
                              hipStream_t stream)
{
    const float* nf    = (const float*)d_in[0];
    const int*   ef    = (const int*)d_in[1];
    const int*   ei    = (const int*)d_in[2];
    const float* epsp  = (const float*)d_in[5];
    const float* be0   = (const float*)d_in[6];
    const float* be1   = (const float*)d_in[7];
    const float* be2   = (const float*)d_in[8];
    const float* W1    = (const float*)d_in[9];
    const float* b1    = (const float*)d_in[10];
    const float* gamma = (const float*)d_in[11];
    const float* beta  = (const float*)d_in[12];
    const float* W2    = (const float*)d_in[13];
    const float* b2v   = (const float*)d_in[14];
    float*       out   = (float*)d_out;

    int N = in_sizes[0] / D;    // 100000
    int E = in_sizes[1] / 3;    // 1600000

    int tiles2 = (N + 31) / 32;           // 3125 (32-row tiles)
    int g2 = 512;                         // 2 blocks/CU (80 KB LDS)

    // workspace layout (4-byte elements); per-bucket M/s partials live
    // in-place in the payload region (dead after k_sortred's LDS copy)
    float* h       = (float*)d_ws;                    // N*64
    float* Mbar    = h + (size_t)N * D;               // 4160
    float* ss      = Mbar + 4160;                     // 256
    float* embsum  = ss + 256;                        // 60*64
    int*   bcursor = (int*)(embsum + 60 * D);         // NBK*16 (line-padded)
    int*   payload = bcursor + NBK * 16;              // NBK*CAP
    float* pM      = (float*)payload;                 // stride CAP per bucket

    k_embsum<<<68, 64, 0, stream>>>(be0, be1, be2, embsum, bcursor);

    int E2 = (E + 1) / 2;
    int gP = (E2 + 1023) / 1024;          // 782 tiles of 2048 edges
    k_part<<<gP, 256, 0, stream>>>(ei, ef, bcursor, payload, E);

    k_sortred<<<NBK, 512, 0, stream>>>(nf, bcursor, payload, embsum, epsp, h, N);

    k_redM<<<65, 256, 0, stream>>>(pM, NBK, Mbar, 1.0f / (float)N);
    k_bn<<<1, 128, 0, stream>>>(Mbar, W1, b1, gamma, beta, ss);

    k_gemm2<<<g2, 256, 0, stream>>>(h, W1, b1, ss, W2, b2v, out, N, tiles2);
}